// Round 1
// baseline (1300.369 us; speedup 1.0000x reference)
//
#include <hip/hip_runtime.h>
#include <math.h>

#define E_DIM 128
#define S_LEN 2048
#define B_N   8
#define BS    (B_N * S_LEN)       // 16384 positions
#define CHUNK 64
#define NCHUNK (S_LEN / CHUNK)    // 32

// ---------------------------------------------------------------------------
// Kernel 1: h = x @ W + b      (BS x 128) @ (128 x 128)
// 256 blocks x 256 thr, 64 rows/block. W staged in LDS (64KB), x read via
// broadcast global loads (L1-hot).
// ---------------------------------------------------------------------------
__global__ __launch_bounds__(256) void k_dense(const float* __restrict__ x,
                                               const float* __restrict__ w,
                                               const float* __restrict__ bias,
                                               float* __restrict__ hout) {
    __shared__ float Wl[E_DIM * E_DIM];   // [k][c], 64KB
    const int t = threadIdx.x;
    const long r0 = (long)blockIdx.x * 64;

    float4* Wl4 = (float4*)Wl;
    const float4* w4 = (const float4*)w;
#pragma unroll
    for (int i = 0; i < 16; ++i) Wl4[t + 256 * i] = w4[t + 256 * i];
    __syncthreads();

    const int cq = t & 31;   // c = 4*cq .. 4*cq+3
    const int rg = t >> 5;   // 8 row-groups of 8 rows
    float4 bb = ((const float4*)bias)[cq];
    float acc[8][4];
#pragma unroll
    for (int i = 0; i < 8; ++i) {
        acc[i][0] = bb.x; acc[i][1] = bb.y; acc[i][2] = bb.z; acc[i][3] = bb.w;
    }
#pragma unroll 4
    for (int k = 0; k < E_DIM; ++k) {
        float4 wv = Wl4[k * 32 + cq];
#pragma unroll
        for (int i = 0; i < 8; ++i) {
            float xv = x[(r0 + rg * 8 + i) * E_DIM + k];   // broadcast within lane-group
            acc[i][0] += xv * wv.x;
            acc[i][1] += xv * wv.y;
            acc[i][2] += xv * wv.z;
            acc[i][3] += xv * wv.w;
        }
    }
    float4* h4 = (float4*)(hout + r0 * E_DIM);
#pragma unroll
    for (int i = 0; i < 8; ++i) {
        float4 o;
        o.x = acc[i][0]; o.y = acc[i][1]; o.z = acc[i][2]; o.w = acc[i][3];
        h4[(rg * 8 + i) * 32 + cq] = o;
    }
}

// ---------------------------------------------------------------------------
// Kernel 2: chunked decayed scan. s_local within each 64-step chunk,
// chunk carry-out f_j written to fc.  s_i = (s_{i-1}+h_{i-1})/1.2, s_0=0.
// grid = B*NCHUNK = 256 blocks x 128 thr (thread = e).
// ---------------------------------------------------------------------------
__global__ __launch_bounds__(128) void k_scan(const float* __restrict__ h,
                                              float* __restrict__ sbuf,
                                              float* __restrict__ fc) {
    const int b = blockIdx.x >> 5;
    const int j = blockIdx.x & 31;
    const int e = threadIdx.x;
    const float inv_d = (float)(1.0 / 1.2);
    long base = ((long)(b * S_LEN + j * CHUNK)) * E_DIM + e;
    float carry = 0.f;
#pragma unroll 4
    for (int i = 0; i < CHUNK; ++i) {
        sbuf[base + (long)i * E_DIM] = carry;           // local prefix (s at this index)
        carry = (carry + h[base + (long)i * E_DIM]) * inv_d;
    }
    fc[(b * NCHUNK + j) * E_DIM + e] = carry;           // f_j
}

// ---------------------------------------------------------------------------
// Kernel 3a: serial carry scan over chunks (exact): carry_{j+1}=f_j+carry_j*d^-64
// fc[j] is replaced in-place by carry INTO chunk j. 1024 threads.
// ---------------------------------------------------------------------------
__global__ __launch_bounds__(256) void k_carry(float* __restrict__ fc, float dm64) {
    int t = blockIdx.x * 256 + threadIdx.x;   // 0..1023 -> (b,e)
    int b = t >> 7, e = t & 127;
    float c = 0.f;
    for (int j = 0; j < NCHUNK; ++j) {
        int idx = (b * NCHUNK + j) * E_DIM + e;
        float v = fc[idx];
        fc[idx] = c;
        c = v + c * dm64;
    }
}

// ---------------------------------------------------------------------------
// Kernel 3b: apply carries: s += carry[b,j,e] * 1.2^-(i within chunk)
// float4 over all BS*E elements.
// ---------------------------------------------------------------------------
__global__ __launch_bounds__(256) void k_fix(float* __restrict__ sbuf,
                                             const float* __restrict__ fc) {
    const float L2D = 0.26303440583379383f;   // log2(1.2)
    int idx4 = blockIdx.x * 256 + threadIdx.x;   // float4 index
    int e4   = idx4 & 31;
    int pos  = idx4 >> 5;
    int sidx = pos & (S_LEN - 1);
    int b    = pos >> 11;
    int i    = sidx & (CHUNK - 1);
    int j    = sidx >> 6;
    float f = exp2f(-L2D * (float)i);
    float4 cv = ((const float4*)fc)[(b * NCHUNK + j) * 32 + e4];
    float4 sv = ((float4*)sbuf)[idx4];
    sv.x += cv.x * f; sv.y += cv.y * f; sv.z += cv.z * f; sv.w += cv.w * f;
    ((float4*)sbuf)[idx4] = sv;
}

// ---------------------------------------------------------------------------
// Kernel 4 (main): out[pos,c] = sum_{a,p} h[pos,a]*s[pos,p]*W[c,a,p],
// then residual + LayerNorm, fused.
// 512 blocks x 256 thr; block owns 32 positions x 128 c.
// Per a: stage W[:,a,:] (64KB) into LDS with XOR-swizzled quads so both the
// staging (coalesced global, linear LDS write) and the compute reads
// (ds_read_b128 across c-strided lanes) are bank-conflict-free.
// Thread tile: 4 rows x 4 cols, c_j = cgrp + 32*j (spread so XOR covers banks).
// ---------------------------------------------------------------------------
__global__ __launch_bounds__(256) void k_main(const float* __restrict__ h,
                                              const float* __restrict__ sbuf,
                                              const float* __restrict__ cmap,
                                              const float* __restrict__ gamma,
                                              const float* __restrict__ beta,
                                              float* __restrict__ out) {
    __shared__ float s_t[32 * E_DIM];     // 16KB
    __shared__ float w_t[E_DIM * E_DIM];  // 64KB, [c][swizzled p-quad]
    const int t = threadIdx.x;
    const long r0 = (long)blockIdx.x * 32;

    // stage s rows (linear, coalesced)
    const float4* s4g = (const float4*)(sbuf + r0 * E_DIM);
    float4* s_t4 = (float4*)s_t;
#pragma unroll
    for (int i = 0; i < 4; ++i) s_t4[t + 256 * i] = s4g[t + 256 * i];

    const int cg = t & 31;   // cgrp: c_j = cg + 32*j
    const int rg = t >> 5;   // 0..7: rows rg*4+i
    float acc[4][4];
#pragma unroll
    for (int i = 0; i < 4; ++i)
#pragma unroll
        for (int j = 0; j < 4; ++j) acc[i][j] = 0.f;

    const float4* cm4 = (const float4*)cmap;
    float4* w_t4 = (float4*)w_t;

    for (int a = 0; a < E_DIM; ++a) {
        __syncthreads();   // previous compute done (also covers s_t staging at a=0)
        // stage W[:, a, :]: storage slot (c, qs) holds global quad qs^(c&31)
#pragma unroll
        for (int it = 0; it < 16; ++it) {
            int c  = (t >> 5) + 8 * it;
            int qs = t & 31;
            int qg = qs ^ (c & 31);
            w_t4[c * 32 + qs] = cm4[(long)c * 4096 + a * 32 + qg];
        }
        __syncthreads();

        float z[4][4];
#pragma unroll
        for (int i = 0; i < 4; ++i)
#pragma unroll
            for (int j = 0; j < 4; ++j) z[i][j] = 0.f;

#pragma unroll 4
        for (int q = 0; q < 32; ++q) {
            float4 wv[4], sv[4];
            int qx = q ^ cg;
#pragma unroll
            for (int j = 0; j < 4; ++j) wv[j] = w_t4[(cg + 32 * j) * 32 + qx];
#pragma unroll
            for (int i = 0; i < 4; ++i) sv[i] = s_t4[(rg * 4 + i) * 32 + q];
#pragma unroll
            for (int i = 0; i < 4; ++i)
#pragma unroll
                for (int j = 0; j < 4; ++j)
                    z[i][j] += sv[i].x * wv[j].x + sv[i].y * wv[j].y +
                               sv[i].z * wv[j].z + sv[i].w * wv[j].w;
        }
#pragma unroll
        for (int i = 0; i < 4; ++i) {
            float hv = h[(r0 + rg * 4 + i) * E_DIM + a];   // broadcast, L1-hot
#pragma unroll
            for (int j = 0; j < 4; ++j) acc[i][j] += hv * z[i][j];
        }
    }

    // residual + LayerNorm (row spread over 32 contiguous lanes, shfl reduce)
    float g[4], bt[4];
#pragma unroll
    for (int j = 0; j < 4; ++j) {
        g[j]  = gamma[cg + 32 * j];
        bt[j] = beta[cg + 32 * j];
    }
#pragma unroll
    for (int i = 0; i < 4; ++i) {
        long r = r0 + rg * 4 + i;
        float v[4];
        float ls = 0.f, lq = 0.f;
#pragma unroll
        for (int j = 0; j < 4; ++j) {
            v[j] = acc[i][j] + h[r * E_DIM + cg + 32 * j];
            ls += v[j];
            lq += v[j] * v[j];
        }
#pragma unroll
        for (int m = 1; m < 32; m <<= 1) {
            ls += __shfl_xor(ls, m, 64);
            lq += __shfl_xor(lq, m, 64);
        }
        float mean = ls * (1.f / 128.f);
        float var  = lq * (1.f / 128.f) - mean * mean;
        float inv  = rsqrtf(var + 1e-3f);
#pragma unroll
        for (int j = 0; j < 4; ++j)
            out[r * E_DIM + cg + 32 * j] = (v[j] - mean) * inv * g[j] + bt[j];
    }
}

// ---------------------------------------------------------------------------
extern "C" void kernel_launch(void* const* d_in, const int* in_sizes, int n_in,
                              void* d_out, int out_size, void* d_ws, size_t ws_size,
                              hipStream_t stream) {
    const float* x     = (const float*)d_in[0];
    const float* dw    = (const float*)d_in[1];
    const float* db    = (const float*)d_in[2];
    const float* cm    = (const float*)d_in[3];
    const float* gamma = (const float*)d_in[4];
    const float* beta  = (const float*)d_in[5];
    float* outp = (float*)d_out;

    float* ws = (float*)d_ws;
    float* h  = ws;                            // BS*E
    float* sb = ws + (size_t)BS * E_DIM;       // BS*E
    float* fc = ws + (size_t)2 * BS * E_DIM;   // B*NCHUNK*E

    float dm64 = (float)pow(1.2, -64.0);       // host-side, pure CPU

    k_dense<<<dim3(BS / 64), dim3(256), 0, stream>>>(x, dw, db, h);
    k_scan <<<dim3(B_N * NCHUNK), dim3(128), 0, stream>>>(h, sb, fc);
    k_carry<<<dim3(4), dim3(256), 0, stream>>>(fc, dm64);
    k_fix  <<<dim3((BS * E_DIM / 4) / 256), dim3(256), 0, stream>>>(sb, fc);
    k_main <<<dim3(BS / 32), dim3(256), 0, stream>>>(h, sb, cm, gamma, beta, outp);
}

// Round 2
// 130.953 us; speedup vs baseline: 9.9301x; 9.9301x over previous
//
#include <hip/hip_runtime.h>
#include <hip/hip_bf16.h>
#include <math.h>

#define E_DIM 128
#define S_LEN 2048
#define B_N   8
#define BS    (B_N * S_LEN)       // 16384 positions
#define CHUNK 64
#define NCHUNK (S_LEN / CHUNK)    // 32

typedef unsigned short u16;
typedef __attribute__((ext_vector_type(8)))  short s8v;    // 8 bf16 (4 VGPRs)
typedef __attribute__((ext_vector_type(16))) float f32x16; // MFMA 32x32 accumulator

// ---------------------------------------------------------------------------
// Kernel 1: h = x @ W + b      (BS x 128) @ (128 x 128)
// ---------------------------------------------------------------------------
__global__ __launch_bounds__(256) void k_dense(const float* __restrict__ x,
                                               const float* __restrict__ w,
                                               const float* __restrict__ bias,
                                               float* __restrict__ hout) {
    __shared__ float Wl[E_DIM * E_DIM];   // [k][c], 64KB
    const int t = threadIdx.x;
    const long r0 = (long)blockIdx.x * 64;

    float4* Wl4 = (float4*)Wl;
    const float4* w4 = (const float4*)w;
#pragma unroll
    for (int i = 0; i < 16; ++i) Wl4[t + 256 * i] = w4[t + 256 * i];
    __syncthreads();

    const int cq = t & 31;   // c = 4*cq .. 4*cq+3
    const int rg = t >> 5;   // 8 row-groups of 8 rows
    float4 bb = ((const float4*)bias)[cq];
    float acc[8][4];
#pragma unroll
    for (int i = 0; i < 8; ++i) {
        acc[i][0] = bb.x; acc[i][1] = bb.y; acc[i][2] = bb.z; acc[i][3] = bb.w;
    }
#pragma unroll 4
    for (int k = 0; k < E_DIM; ++k) {
        float4 wv = Wl4[k * 32 + cq];
#pragma unroll
        for (int i = 0; i < 8; ++i) {
            float xv = x[(r0 + rg * 8 + i) * E_DIM + k];
            acc[i][0] += xv * wv.x;
            acc[i][1] += xv * wv.y;
            acc[i][2] += xv * wv.z;
            acc[i][3] += xv * wv.w;
        }
    }
    float4* h4 = (float4*)(hout + r0 * E_DIM);
#pragma unroll
    for (int i = 0; i < 8; ++i) {
        float4 o;
        o.x = acc[i][0]; o.y = acc[i][1]; o.z = acc[i][2]; o.w = acc[i][3];
        h4[(rg * 8 + i) * 32 + cq] = o;
    }
}

// ---------------------------------------------------------------------------
// Kernel 2: chunked decayed scan (local prefix within 64-step chunks)
// ---------------------------------------------------------------------------
__global__ __launch_bounds__(128) void k_scan(const float* __restrict__ h,
                                              float* __restrict__ sbuf,
                                              float* __restrict__ fc) {
    const int b = blockIdx.x >> 5;
    const int j = blockIdx.x & 31;
    const int e = threadIdx.x;
    const float inv_d = (float)(1.0 / 1.2);
    long base = ((long)(b * S_LEN + j * CHUNK)) * E_DIM + e;
    float carry = 0.f;
#pragma unroll 4
    for (int i = 0; i < CHUNK; ++i) {
        sbuf[base + (long)i * E_DIM] = carry;
        carry = (carry + h[base + (long)i * E_DIM]) * inv_d;
    }
    fc[(b * NCHUNK + j) * E_DIM + e] = carry;
}

// ---------------------------------------------------------------------------
// Kernel 3a: serial carry combine across chunks (exact)
// ---------------------------------------------------------------------------
__global__ __launch_bounds__(256) void k_carry(float* __restrict__ fc, float dm64) {
    int t = blockIdx.x * 256 + threadIdx.x;   // 0..1023 -> (b,e)
    int b = t >> 7, e = t & 127;
    float c = 0.f;
    for (int j = 0; j < NCHUNK; ++j) {
        int idx = (b * NCHUNK + j) * E_DIM + e;
        float v = fc[idx];
        fc[idx] = c;
        c = v + c * dm64;
    }
}

// ---------------------------------------------------------------------------
// Kernel 3b: apply carries: s += carry[b,j,e] * 1.2^-(i within chunk)
// ---------------------------------------------------------------------------
__global__ __launch_bounds__(256) void k_fix(float* __restrict__ sbuf,
                                             const float* __restrict__ fc) {
    const float L2D = 0.26303440583379383f;   // log2(1.2)
    int idx4 = blockIdx.x * 256 + threadIdx.x;
    int e4   = idx4 & 31;
    int pos  = idx4 >> 5;
    int sidx = pos & (S_LEN - 1);
    int b    = pos >> 11;
    int i    = sidx & (CHUNK - 1);
    int j    = sidx >> 6;
    float f = exp2f(-L2D * (float)i);
    float4 cv = ((const float4*)fc)[(b * NCHUNK + j) * 32 + e4];
    float4 sv = ((float4*)sbuf)[idx4];
    sv.x += cv.x * f; sv.y += cv.y * f; sv.z += cv.z * f; sv.w += cv.w * f;
    ((float4*)sbuf)[idx4] = sv;
}

// ---------------------------------------------------------------------------
// Kernel 4: W pre-convert fp32 [c][a][p] -> bf16 [a][c][quad-swizzled p]
// Out quad (a,c,qs) holds source quad (c, a, qs ^ (c&15)) so that k_main's
// LINEAR global_load_lds staging lands the swizzled layout the ds_read side
// expects (XOR is an involution; source-permute == read-permute, G21).
// ---------------------------------------------------------------------------
__global__ __launch_bounds__(256) void k_wconv(const float* __restrict__ cm,
                                               u16* __restrict__ wb) {
    int t = blockIdx.x * 256 + threadIdx.x;     // 0..262143, one 8-elem quad each
    int qs = t & 15, c = (t >> 4) & 127, a = t >> 11;
    const float* src = cm + (((long)(c << 7) + a) << 7) + ((qs ^ (c & 15)) << 3);
    float4 v0 = ((const float4*)src)[0];
    float4 v1 = ((const float4*)src)[1];
    union { __hip_bfloat162 h2[4]; s8v v; } u;
    u.h2[0] = __float22bfloat162_rn(make_float2(v0.x, v0.y));
    u.h2[1] = __float22bfloat162_rn(make_float2(v0.z, v0.w));
    u.h2[2] = __float22bfloat162_rn(make_float2(v1.x, v1.y));
    u.h2[3] = __float22bfloat162_rn(make_float2(v1.z, v1.w));
    ((s8v*)wb)[t] = u.v;   // linear: offset == t*8  (a-major [a][c][p])
}

// ---------------------------------------------------------------------------
// Kernel 5 (main): MFMA einsum.  out[pos,c] += sum_{a in K-half, p}
//   bf16(h[pos,a]*s[pos,p]) * bf16(W[c,a,p])
// Grid 256 = (mb 0..127) x (r 0..1).  Block: 4 waves x 32 rows, full N=128.
// s in 64 VGPRs (loaded once); A-frags generated per a-slice in registers;
// W a-slice (32KB) double-buffered in LDS via global_load_lds width=16.
// Partial sums combined across the two K-halves with hw fp32 atomics.
// ---------------------------------------------------------------------------
__global__ __launch_bounds__(256, 2) void k_main(const float* __restrict__ h,
                                                 const float* __restrict__ sbuf,
                                                 const u16* __restrict__ wb,
                                                 float* __restrict__ out) {
    __shared__ u16 Wl[2][16384];   // 2 x 32KB
    const int t = threadIdx.x;
    const int w = t >> 6;          // wave 0..3
    const int l = t & 63;
    const int l31 = l & 31, hi = l >> 5;
    const int mb = blockIdx.x >> 1, r = blockIdx.x & 1;
    const long gr = (long)mb * 128 + w * 32 + l31;   // this lane's global row

    // --- persistent s fragment: s[gr, p] for p = ks*16 + hi*8 + j ---
    float sreg[64];
    const float4* s4 = (const float4*)(sbuf + gr * E_DIM);
#pragma unroll
    for (int ks = 0; ks < 8; ++ks) {
        float4 v0 = s4[ks * 4 + hi * 2];
        float4 v1 = s4[ks * 4 + hi * 2 + 1];
        sreg[ks*8+0]=v0.x; sreg[ks*8+1]=v0.y; sreg[ks*8+2]=v0.z; sreg[ks*8+3]=v0.w;
        sreg[ks*8+4]=v1.x; sreg[ks*8+5]=v1.y; sreg[ks*8+6]=v1.z; sreg[ks*8+7]=v1.w;
    }

    f32x16 acc[4];
#pragma unroll
    for (int nt = 0; nt < 4; ++nt)
#pragma unroll
        for (int g = 0; g < 16; ++g) acc[nt][g] = 0.f;

    const u16* wbase = wb + (size_t)r * 64 * 16384;   // K-half base
    const int cx = l31 & 15;

    // prologue: stage slice 0 into buf 0
#pragma unroll
    for (int i = 0; i < 8; ++i) {
        const u16* g = wbase + (w * 8 + i) * 512 + l * 8;
        __builtin_amdgcn_global_load_lds((const __attribute__((address_space(1))) void*)g,
            (__attribute__((address_space(3))) void*)&Wl[0][(w * 8 + i) * 512], 16, 0, 0);
    }
    float hv = h[gr * E_DIM + r * 64];
    __syncthreads();   // compiler drains vmcnt before s_barrier

#pragma unroll 1
    for (int sl = 0; sl < 64; ++sl) {
        const int cur = sl & 1;
        if (sl < 63) {
#pragma unroll
            for (int i = 0; i < 8; ++i) {
                const u16* g = wbase + (size_t)(sl + 1) * 16384 + (w * 8 + i) * 512 + l * 8;
                __builtin_amdgcn_global_load_lds((const __attribute__((address_space(1))) void*)g,
                    (__attribute__((address_space(3))) void*)&Wl[cur ^ 1][(w * 8 + i) * 512], 16, 0, 0);
            }
        }
        float hvn = (sl < 63) ? h[gr * E_DIM + r * 64 + sl + 1] : 0.f;

        // A-frags: fp32 product, one bf16 rounding
        s8v af[8];
#pragma unroll
        for (int ks = 0; ks < 8; ++ks) {
            union { __hip_bfloat162 h2[4]; s8v v; } u;
#pragma unroll
            for (int q = 0; q < 4; ++q)
                u.h2[q] = __float22bfloat162_rn(
                    make_float2(hv * sreg[ks*8 + 2*q], hv * sreg[ks*8 + 2*q + 1]));
            af[ks] = u.v;
        }

#pragma unroll
        for (int ks = 0; ks < 8; ++ks) {
            const int dq = ((ks << 1) + hi) ^ cx;   // swizzled quad
#pragma unroll
            for (int nt = 0; nt < 4; ++nt) {
                s8v bf = *(const s8v*)&Wl[cur][(nt * 32 + l31) * 128 + dq * 8];
                acc[nt] = __builtin_amdgcn_mfma_f32_32x32x16_bf16(af[ks], bf, acc[nt], 0, 0, 0);
            }
        }
        hv = hvn;
        __syncthreads();
    }

    // epilogue: accumulate partials into d_out (zeroed by memset; 2 commutative
    // hw fp32 atomic adds per element -> deterministic)
#pragma unroll
    for (int nt = 0; nt < 4; ++nt)
#pragma unroll
        for (int g = 0; g < 16; ++g) {
            int rowl = (g & 3) + 8 * (g >> 2) + 4 * hi;   // m101-verified C/D map
            unsafeAtomicAdd(&out[((long)mb * 128 + w * 32 + rowl) * E_DIM + nt * 32 + l31],
                            acc[nt][g]);
        }
}

// ---------------------------------------------------------------------------
// Kernel 6: residual + LayerNorm, in place on d_out. 8 rows/block.
// ---------------------------------------------------------------------------
__global__ __launch_bounds__(256) void k_ln(float* __restrict__ out,
                                            const float* __restrict__ h,
                                            const float* __restrict__ gamma,
                                            const float* __restrict__ beta) {
    const int t = threadIdx.x;
    const int l32 = t & 31, rl = t >> 5;
    const long row = (long)blockIdx.x * 8 + rl;
    float4 v  = ((const float4*)out)[row * 32 + l32];
    float4 hv = ((const float4*)h)[row * 32 + l32];
    v.x += hv.x; v.y += hv.y; v.z += hv.z; v.w += hv.w;
    float ls = v.x + v.y + v.z + v.w;
    float lq = v.x * v.x + v.y * v.y + v.z * v.z + v.w * v.w;
#pragma unroll
    for (int m = 1; m < 32; m <<= 1) {
        ls += __shfl_xor(ls, m, 64);
        lq += __shfl_xor(lq, m, 64);
    }
    float mean = ls * (1.f / 128.f);
    float var  = lq * (1.f / 128.f) - mean * mean;
    float inv  = rsqrtf(var + 1e-3f);
    float4 g = ((const float4*)gamma)[l32];
    float4 b = ((const float4*)beta)[l32];
    float4 o;
    o.x = (v.x - mean) * inv * g.x + b.x;
    o.y = (v.y - mean) * inv * g.y + b.y;
    o.z = (v.z - mean) * inv * g.z + b.z;
    o.w = (v.w - mean) * inv * g.w + b.w;
    ((float4*)out)[row * 32 + l32] = o;
}

// ---------------------------------------------------------------------------
extern "C" void kernel_launch(void* const* d_in, const int* in_sizes, int n_in,
                              void* d_out, int out_size, void* d_ws, size_t ws_size,
                              hipStream_t stream) {
    const float* x     = (const float*)d_in[0];
    const float* dw    = (const float*)d_in[1];
    const float* db    = (const float*)d_in[2];
    const float* cm    = (const float*)d_in[3];
    const float* gamma = (const float*)d_in[4];
    const float* beta  = (const float*)d_in[5];
    float* outp = (float*)d_out;

    float* ws = (float*)d_ws;
    float* h  = ws;                               // 2M floats
    float* sb = ws + (size_t)BS * E_DIM;          // 2M floats
    float* fc = ws + (size_t)2 * BS * E_DIM;      // 32768 floats
    u16*   wb = (u16*)(ws + (size_t)2 * BS * E_DIM + B_N * NCHUNK * E_DIM); // 2M bf16

    float dm64 = (float)pow(1.2, -64.0);

    hipMemsetAsync(d_out, 0, (size_t)BS * E_DIM * sizeof(float), stream);
    k_wconv<<<dim3(1024), dim3(256), 0, stream>>>(cm, wb);
    k_dense<<<dim3(BS / 64), dim3(256), 0, stream>>>(x, dw, db, h);
    k_scan <<<dim3(B_N * NCHUNK), dim3(128), 0, stream>>>(h, sb, fc);
    k_carry<<<dim3(4), dim3(256), 0, stream>>>(fc, dm64);
    k_fix  <<<dim3((BS * E_DIM / 4) / 256), dim3(256), 0, stream>>>(sb, fc);
    k_main <<<dim3(256), dim3(256), 0, stream>>>(h, sb, wb, outp);
    k_ln   <<<dim3(BS / 8), dim3(256), 0, stream>>>(outp, h, gamma, beta);
}

// Round 3
// 127.996 us; speedup vs baseline: 10.1595x; 1.0231x over previous
//
#include <hip/hip_runtime.h>
#include <hip/hip_bf16.h>
#include <math.h>

#define E_DIM 128
#define S_LEN 2048
#define B_N   8
#define BS    (B_N * S_LEN)       // 16384 positions
#define CHUNK 64
#define NCHUNK (S_LEN / CHUNK)    // 32

typedef unsigned short u16;
typedef _Float16 f16;
typedef _Float16 f16x2 __attribute__((ext_vector_type(2)));
typedef _Float16 f16x8 __attribute__((ext_vector_type(8)));
typedef float    f32x16 __attribute__((ext_vector_type(16)));

// ---------------------------------------------------------------------------
// Kernel 1: h = x @ W + b      (BS x 128) @ (128 x 128), fp32
// ---------------------------------------------------------------------------
__global__ __launch_bounds__(256) void k_dense(const float* __restrict__ x,
                                               const float* __restrict__ w,
                                               const float* __restrict__ bias,
                                               float* __restrict__ hout) {
    __shared__ float Wl[E_DIM * E_DIM];   // [k][c], 64KB
    const int t = threadIdx.x;
    const long r0 = (long)blockIdx.x * 64;

    float4* Wl4 = (float4*)Wl;
    const float4* w4 = (const float4*)w;
#pragma unroll
    for (int i = 0; i < 16; ++i) Wl4[t + 256 * i] = w4[t + 256 * i];
    __syncthreads();

    const int cq = t & 31;
    const int rg = t >> 5;
    float4 bb = ((const float4*)bias)[cq];
    float acc[8][4];
#pragma unroll
    for (int i = 0; i < 8; ++i) {
        acc[i][0] = bb.x; acc[i][1] = bb.y; acc[i][2] = bb.z; acc[i][3] = bb.w;
    }
#pragma unroll 4
    for (int k = 0; k < E_DIM; ++k) {
        float4 wv = Wl4[k * 32 + cq];
#pragma unroll
        for (int i = 0; i < 8; ++i) {
            float xv = x[(r0 + rg * 8 + i) * E_DIM + k];
            acc[i][0] += xv * wv.x;
            acc[i][1] += xv * wv.y;
            acc[i][2] += xv * wv.z;
            acc[i][3] += xv * wv.w;
        }
    }
    float4* h4 = (float4*)(hout + r0 * E_DIM);
#pragma unroll
    for (int i = 0; i < 8; ++i) {
        float4 o;
        o.x = acc[i][0]; o.y = acc[i][1]; o.z = acc[i][2]; o.w = acc[i][3];
        h4[(rg * 8 + i) * 32 + cq] = o;
    }
}

// ---------------------------------------------------------------------------
// Kernel 2: chunked decayed scan. Writes f16 local prefix into sb16, f16
// transposed h into hT[a][pos], fp32 chunk carry-out into fc.
// ---------------------------------------------------------------------------
__global__ __launch_bounds__(128) void k_scan(const float* __restrict__ h,
                                              u16* __restrict__ sb16,
                                              float* __restrict__ fc,
                                              u16* __restrict__ hT) {
    const int b = blockIdx.x >> 5;
    const int j = blockIdx.x & 31;
    const int e = threadIdx.x;
    const float inv_d = (float)(1.0 / 1.2);
    const int pos0 = b * S_LEN + j * CHUNK;
    long base = (long)pos0 * E_DIM + e;
    float carry = 0.f;
    union { u16 u[8]; uint4 v; } hb;
#pragma unroll 1
    for (int i0 = 0; i0 < CHUNK; i0 += 8) {
#pragma unroll
        for (int k = 0; k < 8; ++k) {
            float hv = h[base + (long)(i0 + k) * E_DIM];
            union { f16 f; u16 u; } cu; cu.f = (f16)carry;
            sb16[base + (long)(i0 + k) * E_DIM] = cu.u;
            union { f16 f; u16 u; } hu; hu.f = (f16)hv;
            hb.u[k] = hu.u;
            carry = (carry + hv) * inv_d;
        }
        *(uint4*)&hT[(size_t)e * BS + pos0 + i0] = hb.v;
    }
    fc[(b * NCHUNK + j) * E_DIM + e] = carry;
}

// ---------------------------------------------------------------------------
// Kernel 3a: serial carry combine across chunks (exact, fp32)
// ---------------------------------------------------------------------------
__global__ __launch_bounds__(256) void k_carry(float* __restrict__ fc, float dm64) {
    int t = blockIdx.x * 256 + threadIdx.x;   // 0..1023 -> (b,e)
    int b = t >> 7, e = t & 127;
    float c = 0.f;
    for (int j = 0; j < NCHUNK; ++j) {
        int idx = (b * NCHUNK + j) * E_DIM + e;
        float v = fc[idx];
        fc[idx] = c;
        c = v + c * dm64;
    }
}

// ---------------------------------------------------------------------------
// Kernel 3b: apply carries in fp32, write back f16: s = f16(local + c*1.2^-i)
// One u16x8 group per thread.
// ---------------------------------------------------------------------------
__global__ __launch_bounds__(256) void k_fix(u16* __restrict__ sb16,
                                             const float* __restrict__ fc) {
    const float L2D = 0.26303440583379383f;   // log2(1.2)
    int u = blockIdx.x * 256 + threadIdx.x;   // u16x8 group
    int e8  = u & 15;
    int pos = u >> 4;
    int i = pos & (CHUNK - 1);
    int j = (pos >> 6) & (NCHUNK - 1);
    int b = pos >> 11;
    float f = exp2f(-L2D * (float)i);
    const float4* fp = (const float4*)(fc + ((size_t)(b * NCHUNK + j)) * E_DIM + e8 * 8);
    float4 c0 = fp[0], c1 = fp[1];
    float cs[8] = {c0.x, c0.y, c0.z, c0.w, c1.x, c1.y, c1.z, c1.w};
    uint4* sp = (uint4*)(sb16 + (size_t)pos * E_DIM + e8 * 8);
    union { uint4 v; u16 u[8]; } su; su.v = *sp;
#pragma unroll
    for (int k = 0; k < 8; ++k) {
        union { f16 f; u16 u; } a; a.u = su.u[k];
        union { f16 f; u16 u; } o; o.f = (f16)((float)a.f + cs[k] * f);
        su.u[k] = o.u;
    }
    *sp = su.v;
}

// ---------------------------------------------------------------------------
// Kernel 4: W pre-convert fp32 [c][a][p] -> f16 [a][c][quad-swizzled p].
// Quad (a,c,qs) holds source quad (c,a, qs ^ (c&15)) so k_main's LINEAR
// global_load_lds staging lands the layout the swizzled ds_read expects.
// ---------------------------------------------------------------------------
__global__ __launch_bounds__(256) void k_wconv(const float* __restrict__ cm,
                                               u16* __restrict__ wb) {
    int t = blockIdx.x * 256 + threadIdx.x;     // 0..262143, one 8-elem quad
    int qs = t & 15, c = (t >> 4) & 127, a = t >> 11;
    const float* src = cm + (((long)(c << 7) + a) << 7) + ((qs ^ (c & 15)) << 3);
    float4 v0 = ((const float4*)src)[0];
    float4 v1 = ((const float4*)src)[1];
    union { f16 f[8]; uint4 v; } o;
    o.f[0] = (f16)v0.x; o.f[1] = (f16)v0.y; o.f[2] = (f16)v0.z; o.f[3] = (f16)v0.w;
    o.f[4] = (f16)v1.x; o.f[5] = (f16)v1.y; o.f[6] = (f16)v1.z; o.f[7] = (f16)v1.w;
    ((uint4*)wb)[t] = o.v;   // linear: [a][c][p-quad swizzled]
}

// ---------------------------------------------------------------------------
// Kernel 5 (main): f16 MFMA einsum.
// Grid 256 = (mb 0..63) x (r 0..3).  Block: 512 thr = 8 waves; block owns
// 256 rows x 128 c x 32 a-slices (K-split 4).  Wave (rbp = w>>1, ntp = w&1)
// owns 64 rows x 64 c: each B-frag ds_read feeds 2 MFMAs, each A-frag 2.
// s packed f16x2 in 64 VGPRs (loaded once); A-frags via v_pk_mul_f16.
// W a-slice (32KB) double-buffered via global_load_lds width=16.
// ---------------------------------------------------------------------------
__global__ __launch_bounds__(512, 2) void k_main(const u16* __restrict__ hT,
                                                 const u16* __restrict__ sb16,
                                                 const u16* __restrict__ wb,
                                                 float* __restrict__ out) {
    __shared__ u16 Wl[2][16384];   // 2 x 32KB
    const int t = threadIdx.x;
    const int w = t >> 6, l = t & 63;
    const int l31 = l & 31, hi = l >> 5;
    const int mb = blockIdx.x >> 2, r = blockIdx.x & 3;
    const int rbp = w >> 1, ntp = w & 1;
    const int row0 = mb * 256 + rbp * 64 + l31;    // rb=0 row; rb=1 is +32

    // persistent s fragments: s2[rb][ks*4+q] = (s[row, ks*16+hi*8+2q], ...+1)
    f16x2 s2[2][32];
#pragma unroll
    for (int rb = 0; rb < 2; ++rb) {
        const uint4* sp = (const uint4*)(sb16 + (size_t)(row0 + 32 * rb) * E_DIM + hi * 8);
#pragma unroll
        for (int ks = 0; ks < 8; ++ks) {
            union { uint4 u; f16x2 h2[4]; } uu;
            uu.u = sp[ks * 2];
#pragma unroll
            for (int q = 0; q < 4; ++q) s2[rb][ks * 4 + q] = uu.h2[q];
        }
    }

    f32x16 acc[2][2];
#pragma unroll
    for (int rb = 0; rb < 2; ++rb)
#pragma unroll
        for (int nt = 0; nt < 2; ++nt)
#pragma unroll
            for (int g = 0; g < 16; ++g) acc[rb][nt][g] = 0.f;

    const u16* wbK = wb + (size_t)(r * 32) * 16384;
    const u16* hTb = hT + (size_t)(r * 32) * BS + mb * 256 + rbp * 64 + l31;

#define STAGE(buf, sl) {                                                          \
    const u16* gsrc = wbK + (size_t)(sl) * 16384 + t * 8;                         \
    _Pragma("unroll")                                                             \
    for (int i = 0; i < 4; ++i)                                                   \
        __builtin_amdgcn_global_load_lds(                                         \
            (const __attribute__((address_space(1))) void*)(gsrc + i * 4096),     \
            (__attribute__((address_space(3))) void*)&Wl[buf][t * 8 + i * 4096],  \
            16, 0, 0); }

    STAGE(0, 0);
    u16 h0 = hTb[0], h1 = hTb[32];
    __syncthreads();   // compiler drains vmcnt before s_barrier

    const int sxb = l31 & 15;
    const int wcbase = (ntp * 64 + l31) * E_DIM;

#pragma unroll 1
    for (int sl = 0; sl < 32; ++sl) {
        const int cur = sl & 1;
        if (sl < 31) {
            if (cur) STAGE(0, sl + 1) else STAGE(1, sl + 1);
        }
        u16 nh0 = 0, nh1 = 0;
        if (sl < 31) { nh0 = hTb[(size_t)(sl + 1) * BS]; nh1 = hTb[(size_t)(sl + 1) * BS + 32]; }

        union { u16 u[2]; f16x2 v; } hu0, hu1;
        hu0.u[0] = h0; hu0.u[1] = h0;
        hu1.u[0] = h1; hu1.u[1] = h1;
        const u16* Wc = &Wl[cur][wcbase];
#pragma unroll
        for (int ks = 0; ks < 8; ++ks) {
            const int sx = ((ks << 1) + hi) ^ sxb;
            f16x8 b0 = *(const f16x8*)(Wc + sx * 8);
            f16x8 b1 = *(const f16x8*)(Wc + 32 * E_DIM + sx * 8);
            union { f16x2 h2[4]; f16x8 v; } a0, a1;
#pragma unroll
            for (int q = 0; q < 4; ++q) {
                a0.h2[q] = hu0.v * s2[0][ks * 4 + q];
                a1.h2[q] = hu1.v * s2[1][ks * 4 + q];
            }
            acc[0][0] = __builtin_amdgcn_mfma_f32_32x32x16_f16(a0.v, b0, acc[0][0], 0, 0, 0);
            acc[0][1] = __builtin_amdgcn_mfma_f32_32x32x16_f16(a0.v, b1, acc[0][1], 0, 0, 0);
            acc[1][0] = __builtin_amdgcn_mfma_f32_32x32x16_f16(a1.v, b0, acc[1][0], 0, 0, 0);
            acc[1][1] = __builtin_amdgcn_mfma_f32_32x32x16_f16(a1.v, b1, acc[1][1], 0, 0, 0);
        }
        h0 = nh0; h1 = nh1;
        __syncthreads();
    }
#undef STAGE

    // epilogue: K-split partials via hw fp32 atomics (out pre-zeroed)
#pragma unroll
    for (int rb = 0; rb < 2; ++rb)
#pragma unroll
        for (int nt = 0; nt < 2; ++nt)
#pragma unroll
            for (int g = 0; g < 16; ++g) {
                int rowl = (g & 3) + 8 * (g >> 2) + 4 * hi;   // m101 C/D map
                long row = (long)mb * 256 + rbp * 64 + rb * 32 + rowl;
                int col = ntp * 64 + nt * 32 + l31;
                unsafeAtomicAdd(&out[row * E_DIM + col], acc[rb][nt][g]);
            }
}

// ---------------------------------------------------------------------------
// Kernel 6: residual + LayerNorm, in place on d_out. 8 rows/block.
// ---------------------------------------------------------------------------
__global__ __launch_bounds__(256) void k_ln(float* __restrict__ out,
                                            const float* __restrict__ h,
                                            const float* __restrict__ gamma,
                                            const float* __restrict__ beta) {
    const int t = threadIdx.x;
    const int l32 = t & 31, rl = t >> 5;
    const long row = (long)blockIdx.x * 8 + rl;
    float4 v  = ((const float4*)out)[row * 32 + l32];
    float4 hv = ((const float4*)h)[row * 32 + l32];
    v.x += hv.x; v.y += hv.y; v.z += hv.z; v.w += hv.w;
    float ls = v.x + v.y + v.z + v.w;
    float lq = v.x * v.x + v.y * v.y + v.z * v.z + v.w * v.w;
#pragma unroll
    for (int m = 1; m < 32; m <<= 1) {
        ls += __shfl_xor(ls, m, 64);
        lq += __shfl_xor(lq, m, 64);
    }
    float mean = ls * (1.f / 128.f);
    float var  = lq * (1.f / 128.f) - mean * mean;
    float inv  = rsqrtf(var + 1e-3f);
    float4 g = ((const float4*)gamma)[l32];
    float4 b = ((const float4*)beta)[l32];
    float4 o;
    o.x = (v.x - mean) * inv * g.x + b.x;
    o.y = (v.y - mean) * inv * g.y + b.y;
    o.z = (v.z - mean) * inv * g.z + b.z;
    o.w = (v.w - mean) * inv * g.w + b.w;
    ((float4*)out)[row * 32 + l32] = o;
}

// ---------------------------------------------------------------------------
extern "C" void kernel_launch(void* const* d_in, const int* in_sizes, int n_in,
                              void* d_out, int out_size, void* d_ws, size_t ws_size,
                              hipStream_t stream) {
    const float* x     = (const float*)d_in[0];
    const float* dw    = (const float*)d_in[1];
    const float* db    = (const float*)d_in[2];
    const float* cm    = (const float*)d_in[3];
    const float* gamma = (const float*)d_in[4];
    const float* beta  = (const float*)d_in[5];
    float* outp = (float*)d_out;

    float* ws = (float*)d_ws;
    float* h   = ws;                                          // BS*E f32 (8 MB)
    float* fc  = ws + (size_t)BS * E_DIM;                     // 32768 f32
    u16*   wb  = (u16*)(fc + B_N * NCHUNK * E_DIM);           // E^3 f16 (4 MB)
    u16*   hT  = wb + (size_t)E_DIM * E_DIM * E_DIM / 2;      // wait: E^3 elems
    // NOTE: wb holds E*E*E = 2097152 f16 elements
    hT = wb + (size_t)2097152;                                // [a][pos] f16 (4 MB)
    u16*   sb16 = hT + (size_t)BS * E_DIM;                    // [pos][p] f16 (4 MB)

    float dm64 = (float)pow(1.2, -64.0);   // host-side, pure CPU

    hipMemsetAsync(d_out, 0, (size_t)BS * E_DIM * sizeof(float), stream);
    k_wconv<<<dim3(1024), dim3(256), 0, stream>>>(cm, wb);
    k_dense<<<dim3(BS / 64), dim3(256), 0, stream>>>(x, dw, db, h);
    k_scan <<<dim3(B_N * NCHUNK), dim3(128), 0, stream>>>(h, sb16, fc, hT);
    k_carry<<<dim3(4), dim3(256), 0, stream>>>(fc, dm64);
    k_fix  <<<dim3((BS * E_DIM / 8) / 256), dim3(256), 0, stream>>>(sb16, fc);
    k_main <<<dim3(256), dim3(512), 0, stream>>>(hT, sb16, wb, outp);
    k_ln   <<<dim3(BS / 8), dim3(256), 0, stream>>>(outp, h, gamma, beta);
}